// Round 2
// baseline (225.358 us; speedup 1.0000x reference)
//
#include <hip/hip_runtime.h>
#include <hip/hip_cooperative_groups.h>
#include <cstdint>

namespace cg = cooperative_groups;

typedef _Float16 f16;
typedef _Float16 f16x2 __attribute__((ext_vector_type(2)));
typedef _Float16 f16x4 __attribute__((ext_vector_type(4)));
typedef _Float16 f16x8 __attribute__((ext_vector_type(8)));
typedef float    f32x4 __attribute__((ext_vector_type(4)));
typedef unsigned short u16;
typedef unsigned int   u32;
typedef unsigned long long u64;

#define LOG2E 1.44269504088896340736f

__device__ __forceinline__ f16x2 habs2(f16x2 v) {
    union { f16x2 h; u32 u; } x; x.h = v; x.u &= 0x7FFF7FFFu; return x.h;
}
#if __has_builtin(__builtin_amdgcn_fdot2)
__device__ __forceinline__ float fdot2f(f16x2 a, f16x2 b, float c) {
    return __builtin_amdgcn_fdot2(a, b, c, false);
}
#else
__device__ __forceinline__ float fdot2f(f16x2 a, f16x2 b, float c) {
    return c + (float)a.x * (float)b.x + (float)a.y * (float)b.y;
}
#endif
#if __has_builtin(__builtin_amdgcn_exp2f)
#define EXP2F __builtin_amdgcn_exp2f
#else
#define EXP2F exp2f
#endif

// ---------------------------------------------------------------------------
// Single cooperative kernel. grid 256 x 512; block owns nodes i0..i0+3.
//
// Phase A (projections, t<384 does W-dots; waves 6-7 build adj bitmask):
//   thread t -> (wsel = t>>7 selects W_l/W_r/W_v, col = t&127 output column).
//   W f32 columns read directly (coalesced per k), cvt f16 in regs.
//   Outputs (global, for all consumers):
//     WrL f16 [4h][8c][1024 j][4 l]  (d = 4c+l; coalesced phase-1 loads)
//     VL  f16 [4h][32 d][1024 j]     (MFMA B-frag layout)
//     BR  f32 [4 h][1024 j] = sum_d 0.6*a_d*Wrh[j,h,d]
//   Outputs (LDS, consumed only by this block):
//     WlS f16 [4][128], ALs f32 [4][4] = sum_d 0.6*a_d*Wlh[i,h,d]
//     amaskS u64 [4][16]  (adj row bitmask, built by waves 6-7 via ballot)
//
// grid.sync() (+ device fences for cross-XCD L2 visibility)
//
// Phase B (attention): 8 waves, wave w -> (head hh = w&3, j-half = w>>2).
//   e[i,j,h] = ALs[i,h] + BR[h,j] + sum_d (0.4 a_d)|Wlh+Wrh|
//   softmax over j, agg via MFMA 16x16x32, LayerNorm + ReLU.
// ---------------------------------------------------------------------------
__global__ __launch_bounds__(512) void GATv2Layer_84447646974220_kernel(
        const float* __restrict__ Wl, const float* __restrict__ Wr,
        const float* __restrict__ Wv, const float* __restrict__ h,
        const int* __restrict__ adj, const float* __restrict__ a_,
        const float* __restrict__ ln_g, const float* __restrict__ ln_b,
        f16* __restrict__ WrL, f16* __restrict__ VL, float* __restrict__ BR,
        float* __restrict__ out) {

    __shared__ __align__(16) f16 ep[4][4][1024];   // [head][row][j]  32768 B
    __shared__ float aggS[2][4][128];              // [half][row][col] 4096 B
    __shared__ float redM[2][4][4];                // [half][head][row]
    __shared__ float redS[2][4][4];
    __shared__ __align__(16) f16 WlS[4][128];      // Wlh rows, block-local
    __shared__ __align__(16) f16 hS[4][128];       // h rows (phase A)
    __shared__ float ALs[4][4];                    // [row][head]
    __shared__ u64 amaskS[4][16];                  // adj bitmask [row][j/64]

    const int t    = threadIdx.x;
    const int lane = t & 63;
    const int i0   = blockIdx.x * 4;

    // ---- phase A: stage h rows (all 512 threads, 1 elem each) ----
    ((f16*)hS)[t] = (f16)h[i0 * 128 + t];

    f16x2 w2[64];
    float asc = 0.f;
    const int wsel = t >> 7, col = t & 127;
    if (t < 384) {
        const float* W = (wsel == 0) ? Wl : ((wsel == 1) ? Wr : Wv);
        #pragma unroll
        for (int c2 = 0; c2 < 64; c2++) {
            f16x2 v;
            v.x = (f16)W[(2 * c2) * 128 + col];
            v.y = (f16)W[(2 * c2 + 1) * 128 + col];
            w2[c2] = v;
        }
        asc = 0.6f * a_[col & 31];
    } else {
        // waves 6-7: build adjacency bitmask for this block's 4 rows
        const int lw = t - 384;          // 0..127
        const int wv = lw >> 6;          // 0: rows 0-1, 1: rows 2-3
        const int ln = lw & 63;
        #pragma unroll
        for (int r = 0; r < 2; r++) {
            const int ii = wv * 2 + r;
            #pragma unroll 1
            for (int c = 0; c < 16; c++) {
                int av = adj[(i0 + ii) * 1024 + c * 64 + ln];
                u64 m = __ballot(av != 0);
                if (ln == 0) amaskS[ii][c] = m;
            }
        }
    }
    __syncthreads();

    if (t < 384) {
        #pragma unroll
        for (int i = 0; i < 4; i++) {
            const int j = i0 + i;
            const f16x2* hr = (const f16x2*)hS[i];
            float acc = 0.f;
            #pragma unroll
            for (int c2 = 0; c2 < 64; c2++) acc = fdot2f(hr[c2], w2[c2], acc);
            const f16 hv = (f16)acc;
            const int hh = col >> 5, dd = col & 31;
            if (wsel == 0) {
                WlS[i][col] = hv;
                float part = asc * acc;
                #pragma unroll
                for (int off = 1; off < 32; off <<= 1) part += __shfl_xor(part, off);
                if ((t & 31) == 0) ALs[i][hh] = part;
            } else if (wsel == 1) {
                WrL[((hh * 8 + (dd >> 2)) * 1024 + j) * 4 + (dd & 3)] = hv;
                float part = asc * acc;
                #pragma unroll
                for (int off = 1; off < 32; off <<= 1) part += __shfl_xor(part, off);
                if ((t & 31) == 0) BR[hh * 1024 + j] = part;
            } else {
                VL[(hh * 32 + dd) * 1024 + j] = hv;
            }
        }
    }

    // ---- grid-wide exchange barrier (cross-XCD visibility via fences) ----
    __threadfence();
    cg::this_grid().sync();
    __threadfence();

    // ---- phase B ----
    const int w    = t >> 6;        // 0..7
    const int hh   = w & 3;         // head
    const int half = w >> 2;        // j-half (0: j<512, 1: j>=512)

    f16x2 q2[16];
    #pragma unroll
    for (int d2 = 0; d2 < 16; d2++) {
        f16x2 q; q.x = (f16)(0.4f * a_[2 * d2]); q.y = (f16)(0.4f * a_[2 * d2 + 1]);
        q2[d2] = q;
    }
    f16x2 wl2[4][16];
    float al[4];
    #pragma unroll
    for (int ii = 0; ii < 4; ii++) {
        const f16x2* src = (const f16x2*)&WlS[ii][hh * 32];
        #pragma unroll
        for (int c2 = 0; c2 < 16; c2++) wl2[ii][c2] = src[c2];
        al[ii] = ALs[ii][hh];
    }

    // ---- phase 1: scores e[i][j] for this wave's (head, j-half) ----
    float maxE[4];
    #pragma unroll
    for (int ii = 0; ii < 4; ii++) maxE[ii] = -__builtin_inff();

    #pragma unroll 1
    for (int jb = 0; jb < 8; jb++) {
        int j = half * 512 + jb * 64 + lane;
        f16x4 wr[8];
        #pragma unroll
        for (int c = 0; c < 8; c++)
            wr[c] = *(const f16x4*)(WrL + ((hh * 8 + c) * 1024 + j) * 4);
        u64 wm[4];
        #pragma unroll
        for (int ii = 0; ii < 4; ii++) wm[ii] = amaskS[ii][half * 8 + jb];
        float bj = BR[hh * 1024 + j];

        float e[4];
        #pragma unroll
        for (int ii = 0; ii < 4; ii++) e[ii] = al[ii];
        #pragma unroll
        for (int c = 0; c < 8; c++) {
            #pragma unroll
            for (int ii = 0; ii < 4; ii++) {
                f16x2 t0 = wl2[ii][2 * c]     + wr[c].lo;
                f16x2 t1 = wl2[ii][2 * c + 1] + wr[c].hi;
                e[ii] = fdot2f(q2[2 * c],     habs2(t0), e[ii]);
                e[ii] = fdot2f(q2[2 * c + 1], habs2(t1), e[ii]);
            }
        }
        #pragma unroll
        for (int ii = 0; ii < 4; ii++) {
            bool ok = (wm[ii] >> lane) & 1ull;
            float v = ok ? (e[ii] + bj) : -__builtin_inff();
            maxE[ii] = fmaxf(maxE[ii], v);
            ep[hh][ii][j] = (f16)v;
        }
    }

    // ---- phase 2: softmax (cross-half max/sum through LDS) ----
    #pragma unroll
    for (int ii = 0; ii < 4; ii++) {
        float M = maxE[ii];
        #pragma unroll
        for (int off = 32; off > 0; off >>= 1) M = fmaxf(M, __shfl_xor(M, off));
        if (lane == 0) redM[half][hh][ii] = M;
    }
    __syncthreads();

    #pragma unroll
    for (int ii = 0; ii < 4; ii++) {
        float M = fmaxf(redM[0][hh][ii], redM[1][hh][ii]);
        f16x8 v0 = *(f16x8*)&ep[hh][ii][half * 512 + lane * 8];
        float pb[8], l = 0.f;
        #pragma unroll
        for (int e = 0; e < 8; e++) pb[e] = EXP2F(((float)v0[e] - M) * LOG2E);
        #pragma unroll
        for (int e = 0; e < 8; e++) { v0[e] = (f16)pb[e]; l += pb[e]; }
        *(f16x8*)&ep[hh][ii][half * 512 + lane * 8] = v0;
        #pragma unroll
        for (int off = 32; off > 0; off >>= 1) l += __shfl_xor(l, off);
        if (lane == 0) redS[half][hh][ii] = l;
    }
    __syncthreads();

    float lr[4];
    #pragma unroll
    for (int ii = 0; ii < 4; ii++)
        lr[ii] = 1.0f / (redS[0][hh][ii] + redS[1][hh][ii]);

    // ---- phase 3: agg = p @ V via MFMA ----
    // A-frag: A[m=lane&15][k=(lane>>4)*8+jj]; rows 4..15 duplicate rows 0..3
    // (m3 = lane&3) — garbage C-rows discarded. B-frag: B[k][n=lane&15] from
    // VL[d=n][j=k] (contiguous j). C/D: col=lane&15, row=(lane>>4)*4+reg.
    f32x4 acc0 = {0.f, 0.f, 0.f, 0.f}, acc1 = {0.f, 0.f, 0.f, 0.f};
    const int q8  = (lane >> 4) << 3;
    const int m3  = lane & 3;
    const int n15 = lane & 15;

    #pragma unroll 1
    for (int jt4 = 0; jt4 < 4; jt4++) {
        int jt = half * 4 + jt4;
        #pragma unroll
        for (int kk = 0; kk < 4; kk++) {
            int ko = jt * 128 + kk * 32 + q8;
            f16x8 af = *(const f16x8*)&ep[hh][m3][ko];
            f16x8 b0 = *(const f16x8*)(VL + (hh * 32 + n15) * 1024 + ko);
            f16x8 b1 = *(const f16x8*)(VL + (hh * 32 + 16 + n15) * 1024 + ko);
            acc0 = __builtin_amdgcn_mfma_f32_16x16x32_f16(af, b0, acc0, 0, 0, 0);
            acc1 = __builtin_amdgcn_mfma_f32_16x16x32_f16(af, b1, acc1, 0, 0, 0);
        }
    }

    if (lane < 16) {
        #pragma unroll
        for (int r = 0; r < 4; r++) {
            aggS[half][r][hh * 32 + lane]      = acc0[r] * lr[r];
            aggS[half][r][hh * 32 + 16 + lane] = acc1[r] * lr[r];
        }
    }
    __syncthreads();

    // ---- phase 4: LayerNorm + ReLU (waves 0..3, one node-row each) ----
    if (w < 4) {
        float x0 = aggS[0][w][lane]      + aggS[1][w][lane];
        float x1 = aggS[0][w][lane + 64] + aggS[1][w][lane + 64];
        float s = x0 + x1, sq = x0 * x0 + x1 * x1;
        #pragma unroll
        for (int off = 32; off > 0; off >>= 1) {
            s  += __shfl_xor(s, off);
            sq += __shfl_xor(sq, off);
        }
        float mean = s * (1.f / 128.f);
        float var  = sq * (1.f / 128.f) - mean * mean;
        float rs   = rsqrtf(var + 1e-5f);
        float y0 = fmaxf((x0 - mean) * rs * ln_g[lane]      + ln_b[lane],      0.f);
        float y1 = fmaxf((x1 - mean) * rs * ln_g[lane + 64] + ln_b[lane + 64], 0.f);
        out[(i0 + w) * 128 + lane]      = y0;
        out[(i0 + w) * 128 + 64 + lane] = y1;
    }
}

// ---------------------------------------------------------------------------
extern "C" void kernel_launch(void* const* d_in, const int* in_sizes, int n_in,
                              void* d_out, int out_size, void* d_ws, size_t ws_size,
                              hipStream_t stream) {
    const float* h   = (const float*)d_in[0];
    const int*   adj = (const int*)d_in[1];
    const float* Wl  = (const float*)d_in[2];
    const float* Wr  = (const float*)d_in[3];
    const float* Wv  = (const float*)d_in[4];
    const float* a_  = (const float*)d_in[5];
    const float* g_  = (const float*)d_in[6];
    const float* b_  = (const float*)d_in[7];
    float* out = (float*)d_out;

    char* ws = (char*)d_ws;
    f16*   WrL = (f16*)(ws);                 // [4][8][1024][4] = 262144 B
    f16*   VL  = (f16*)(ws + 262144);        // [4][32][1024]   = 262144 B
    float* BR  = (float*)(ws + 524288);      // [4][1024] f32   =  16384 B

    void* args[] = {
        (void*)&Wl, (void*)&Wr, (void*)&Wv, (void*)&h, (void*)&adj,
        (void*)&a_, (void*)&g_, (void*)&b_, (void*)&WrL, (void*)&VL,
        (void*)&BR, (void*)&out
    };
    hipLaunchCooperativeKernel((const void*)GATv2Layer_84447646974220_kernel,
                               dim3(256), dim3(512), args, 0, stream);
}

// Round 3
// 104.809 us; speedup vs baseline: 2.1502x; 2.1502x over previous
//
#include <hip/hip_runtime.h>
#include <cstdint>

typedef _Float16 f16;
typedef _Float16 f16x2 __attribute__((ext_vector_type(2)));
typedef _Float16 f16x4 __attribute__((ext_vector_type(4)));
typedef _Float16 f16x8 __attribute__((ext_vector_type(8)));
typedef float    f32x4 __attribute__((ext_vector_type(4)));
typedef unsigned short u16;
typedef unsigned int   u32;
typedef unsigned long long u64;

#define LOG2E 1.44269504088896340736f

__device__ __forceinline__ f16x2 habs2(f16x2 v) {
    union { f16x2 h; u32 u; } x; x.h = v; x.u &= 0x7FFF7FFFu; return x.h;
}
#if __has_builtin(__builtin_amdgcn_fdot2)
__device__ __forceinline__ float fdot2f(f16x2 a, f16x2 b, float c) {
    return __builtin_amdgcn_fdot2(a, b, c, false);
}
#else
__device__ __forceinline__ float fdot2f(f16x2 a, f16x2 b, float c) {
    return c + (float)a.x * (float)b.x + (float)a.y * (float)b.y;
}
#endif
#if __has_builtin(__builtin_amdgcn_exp2f)
#define EXP2F __builtin_amdgcn_exp2f
#else
#define EXP2F exp2f
#endif

// ---------------------------------------------------------------------------
// K1: fused prep + projections + adjacency compression.
// grid 256 x 512; block owns nodes i0..i0+3.
//   t < 384 : (wsel = t>>7 selects W_l/W_r/W_v, col = t&127 output column).
//             W f32 columns read directly (coalesced per k), cvt f16 in regs.
//   t >= 384: waves 6-7 ballot-compress this block's 4 adj rows into AM.
// Outputs:
//   Wlh f16 [j][128]               (o = h*32+d)
//   WrL f16 [4h][1024 j][32 d]     (row-contiguous: k2 loads 4x dwordx4/lane)
//   VL  f16 [4h][32 d][1024 j]     (MFMA B-frag: 8 contiguous j at fixed d)
//   AL  f32 [1024 i][4 h] = sum_d 0.6*a_d*Wlh[i,h,d]
//   BR  f32 [4 h][1024 j] = sum_d 0.6*a_d*Wrh[j,h,d]
//   AM  u64 [1024 i][16 c]          (adj bitmask, bit ln of word c = adj[i][c*64+ln])
// ---------------------------------------------------------------------------
__global__ __launch_bounds__(512) void k1_proj(
        const float* __restrict__ Wl, const float* __restrict__ Wr,
        const float* __restrict__ Wv, const float* __restrict__ h,
        const float* __restrict__ a_, const int* __restrict__ adj,
        f16* __restrict__ Wlh, f16* __restrict__ WrL, f16* __restrict__ VL,
        float* __restrict__ AL, float* __restrict__ BR, u64* __restrict__ AM) {
    __shared__ __align__(16) f16 hS[4][128];
    const int t  = threadIdx.x;
    const int i0 = blockIdx.x * 4;

    // stage 4 h-rows to LDS as f16 (512 values, 1 per thread)
    ((f16*)hS)[t] = (f16)h[i0 * 128 + t];

    f16x2 w2[64];
    float asc = 0.f;
    const int wsel = t >> 7, col = t & 127;
    if (t < 384) {
        const float* W = (wsel == 0) ? Wl : ((wsel == 1) ? Wr : Wv);
        #pragma unroll
        for (int c2 = 0; c2 < 64; c2++) {
            f16x2 v;
            v.x = (f16)W[(2 * c2) * 128 + col];
            v.y = (f16)W[(2 * c2 + 1) * 128 + col];
            w2[c2] = v;
        }
        asc = 0.6f * a_[col & 31];
    } else {
        // waves 6-7: compress adjacency rows i0..i0+3 into bitmasks
        const int lw = t - 384;          // 0..127
        const int wv = lw >> 6;          // 0: rows 0-1, 1: rows 2-3
        const int ln = lw & 63;
        #pragma unroll
        for (int r = 0; r < 2; r++) {
            const int ii = wv * 2 + r;
            #pragma unroll 1
            for (int c = 0; c < 16; c++) {
                int av = adj[(i0 + ii) * 1024 + c * 64 + ln];
                u64 m = __ballot(av != 0);
                if (ln == 0) AM[(i0 + ii) * 16 + c] = m;
            }
        }
    }
    __syncthreads();

    if (t < 384) {
        #pragma unroll
        for (int i = 0; i < 4; i++) {
            const int j = i0 + i;
            const f16x2* hr = (const f16x2*)hS[i];
            float acc = 0.f;
            #pragma unroll
            for (int c2 = 0; c2 < 64; c2++) acc = fdot2f(hr[c2], w2[c2], acc);
            const f16 hv = (f16)acc;
            const int hh = col >> 5, dd = col & 31;
            if (wsel == 0) {
                Wlh[j * 128 + col] = hv;
                float part = asc * acc;
                #pragma unroll
                for (int off = 1; off < 32; off <<= 1) part += __shfl_xor(part, off);
                if ((t & 31) == 0) AL[j * 4 + hh] = part;
            } else if (wsel == 1) {
                WrL[(hh * 1024 + j) * 32 + dd] = hv;
                float part = asc * acc;
                #pragma unroll
                for (int off = 1; off < 32; off <<= 1) part += __shfl_xor(part, off);
                if ((t & 31) == 0) BR[hh * 1024 + j] = part;
            } else {
                VL[(hh * 32 + dd) * 1024 + j] = hv;
            }
        }
    }
}

// ---------------------------------------------------------------------------
// K2: fused GATv2 attention + MFMA aggregation + LayerNorm + ReLU.
// grid 256 x 512. Block = 4 nodes i. 8 waves: wave w -> (head hh = w&3,
// j-half = w>>2). LDS 37 KB.
// Score: e[i,j,h] = AL[i,h] + BR[h,j] + sum_d (0.4 a_d)|Wlh+Wrh|
// adj comes in as a wave-uniform bitmask (scalar loads, no per-lane VMEM).
// ---------------------------------------------------------------------------
__global__ __launch_bounds__(512) void GATv2Layer_84447646974220_kernel(
        const f16* __restrict__ Wlh, const f16* __restrict__ WrL,
        const f16* __restrict__ VL,  const u64* __restrict__ AM,
        const float* __restrict__ AL, const float* __restrict__ BR,
        const float* __restrict__ a_, const float* __restrict__ ln_g,
        const float* __restrict__ ln_b, float* __restrict__ out) {

    __shared__ __align__(16) f16 ep[4][4][1024];   // [head][row][j]  32768 B
    __shared__ float aggS[2][4][128];              // [half][row][col] 4096 B
    __shared__ float redM[2][4][4];                // [half][head][row]
    __shared__ float redS[2][4][4];

    const int t    = threadIdx.x;
    const int w    = t >> 6;        // 0..7
    const int lane = t & 63;
    const int hh   = w & 3;         // head
    const int half = w >> 2;        // j-half (0: j<512, 1: j>=512)
    const int i0   = blockIdx.x * 4;

    // per-wave constants: q2 = 0.4*a (f16 pairs), Wl head-slices, AL terms
    f16x2 q2[16];
    #pragma unroll
    for (int d2 = 0; d2 < 16; d2++) {
        f16x2 q; q.x = (f16)(0.4f * a_[2 * d2]); q.y = (f16)(0.4f * a_[2 * d2 + 1]);
        q2[d2] = q;
    }
    f16x2 wl2[4][16];
    float al[4];
    #pragma unroll
    for (int ii = 0; ii < 4; ii++) {
        const f16x2* src = (const f16x2*)(Wlh + (i0 + ii) * 128 + hh * 32);
        #pragma unroll
        for (int c2 = 0; c2 < 16; c2++) wl2[ii][c2] = src[c2];
        al[ii] = AL[(i0 + ii) * 4 + hh];          // wave-uniform broadcast
    }

    // ---- phase 1: scores e[i][j] for this wave's (head, j-half) ----
    float maxE[4];
    #pragma unroll
    for (int ii = 0; ii < 4; ii++) maxE[ii] = -__builtin_inff();

    #pragma unroll 1
    for (int jb = 0; jb < 8; jb++) {
        int j = half * 512 + jb * 64 + lane;
        // WrL row for this j: 64 B contiguous per lane -> 4 x dwordx4
        union { f16x8 v8; f16x2 v2[4]; } wu[4];
        const f16* wp = WrL + (hh * 1024 + j) * 32;
        #pragma unroll
        for (int c8 = 0; c8 < 4; c8++) wu[c8].v8 = *(const f16x8*)(wp + c8 * 8);
        // adjacency bitmasks: wave-uniform address -> scalar loads
        u64 wm[4];
        #pragma unroll
        for (int ii = 0; ii < 4; ii++) {
            int mi = __builtin_amdgcn_readfirstlane((i0 + ii) * 16 + half * 8 + jb);
            wm[ii] = AM[mi];
        }
        float bj = BR[hh * 1024 + j];

        float e[4];
        #pragma unroll
        for (int ii = 0; ii < 4; ii++) e[ii] = al[ii];
        #pragma unroll
        for (int c2 = 0; c2 < 16; c2++) {
            f16x2 wrp = wu[c2 >> 2].v2[c2 & 3];
            #pragma unroll
            for (int ii = 0; ii < 4; ii++) {
                f16x2 t0 = wl2[ii][c2] + wrp;
                e[ii] = fdot2f(q2[c2], habs2(t0), e[ii]);
            }
        }
        #pragma unroll
        for (int ii = 0; ii < 4; ii++) {
            bool ok = (wm[ii] >> lane) & 1ull;
            float v = ok ? (e[ii] + bj) : -__builtin_inff();
            maxE[ii] = fmaxf(maxE[ii], v);
            ep[hh][ii][j] = (f16)v;
        }
    }

    // ---- phase 2: softmax (cross-half max/sum through LDS) ----
    #pragma unroll
    for (int ii = 0; ii < 4; ii++) {
        float M = maxE[ii];
        #pragma unroll
        for (int off = 32; off > 0; off >>= 1) M = fmaxf(M, __shfl_xor(M, off));
        if (lane == 0) redM[half][hh][ii] = M;
    }
    __syncthreads();

    #pragma unroll
    for (int ii = 0; ii < 4; ii++) {
        float M = fmaxf(redM[0][hh][ii], redM[1][hh][ii]);
        f16x8 v0 = *(f16x8*)&ep[hh][ii][half * 512 + lane * 8];
        float pb[8], l = 0.f;
        #pragma unroll
        for (int e = 0; e < 8; e++) pb[e] = EXP2F(((float)v0[e] - M) * LOG2E);
        #pragma unroll
        for (int e = 0; e < 8; e++) { v0[e] = (f16)pb[e]; l += pb[e]; }
        *(f16x8*)&ep[hh][ii][half * 512 + lane * 8] = v0;
        #pragma unroll
        for (int off = 32; off > 0; off >>= 1) l += __shfl_xor(l, off);
        if (lane == 0) redS[half][hh][ii] = l;
    }
    __syncthreads();

    float lr[4];
    #pragma unroll
    for (int ii = 0; ii < 4; ii++)
        lr[ii] = 1.0f / (redS[0][hh][ii] + redS[1][hh][ii]);

    // ---- phase 3: agg = p @ V via MFMA ----
    // A-frag: A[m=lane&15][k=(lane>>4)*8+jj]; rows 4..15 duplicate rows 0..3
    // (m3 = lane&3) — garbage C-rows discarded. B-frag: B[k][n=lane&15] from
    // VL[d=n][j=k] (contiguous j). C/D: col=lane&15, row=(lane>>4)*4+reg.
    f32x4 acc0 = {0.f, 0.f, 0.f, 0.f}, acc1 = {0.f, 0.f, 0.f, 0.f};
    const int q8  = (lane >> 4) << 3;
    const int m3  = lane & 3;
    const int n15 = lane & 15;

    #pragma unroll 1
    for (int jt4 = 0; jt4 < 4; jt4++) {
        int jt = half * 4 + jt4;
        #pragma unroll
        for (int kk = 0; kk < 4; kk++) {
            int ko = jt * 128 + kk * 32 + q8;
            f16x8 af = *(const f16x8*)&ep[hh][m3][ko];
            f16x8 b0 = *(const f16x8*)(VL + (hh * 32 + n15) * 1024 + ko);
            f16x8 b1 = *(const f16x8*)(VL + (hh * 32 + 16 + n15) * 1024 + ko);
            acc0 = __builtin_amdgcn_mfma_f32_16x16x32_f16(af, b0, acc0, 0, 0, 0);
            acc1 = __builtin_amdgcn_mfma_f32_16x16x32_f16(af, b1, acc1, 0, 0, 0);
        }
    }

    if (lane < 16) {
        #pragma unroll
        for (int r = 0; r < 4; r++) {
            aggS[half][r][hh * 32 + lane]      = acc0[r] * lr[r];
            aggS[half][r][hh * 32 + 16 + lane] = acc1[r] * lr[r];
        }
    }
    __syncthreads();

    // ---- phase 4: LayerNorm + ReLU (waves 0..3, one node-row each) ----
    if (w < 4) {
        float x0 = aggS[0][w][lane]      + aggS[1][w][lane];
        float x1 = aggS[0][w][lane + 64] + aggS[1][w][lane + 64];
        float s = x0 + x1, sq = x0 * x0 + x1 * x1;
        #pragma unroll
        for (int off = 32; off > 0; off >>= 1) {
            s  += __shfl_xor(s, off);
            sq += __shfl_xor(sq, off);
        }
        float mean = s * (1.f / 128.f);
        float var  = sq * (1.f / 128.f) - mean * mean;
        float rs   = rsqrtf(var + 1e-5f);
        float y0 = fmaxf((x0 - mean) * rs * ln_g[lane]      + ln_b[lane],      0.f);
        float y1 = fmaxf((x1 - mean) * rs * ln_g[lane + 64] + ln_b[lane + 64], 0.f);
        out[(i0 + w) * 128 + lane]      = y0;
        out[(i0 + w) * 128 + 64 + lane] = y1;
    }
}

// ---------------------------------------------------------------------------
extern "C" void kernel_launch(void* const* d_in, const int* in_sizes, int n_in,
                              void* d_out, int out_size, void* d_ws, size_t ws_size,
                              hipStream_t stream) {
    const float* h   = (const float*)d_in[0];
    const int*   adj = (const int*)d_in[1];
    const float* Wl  = (const float*)d_in[2];
    const float* Wr  = (const float*)d_in[3];
    const float* Wv  = (const float*)d_in[4];
    const float* a_  = (const float*)d_in[5];
    const float* g_  = (const float*)d_in[6];
    const float* b_  = (const float*)d_in[7];
    float* out = (float*)d_out;

    char* ws = (char*)d_ws;
    f16*   Wlh = (f16*)(ws);                 // 1024*128 f16     = 262144 B
    f16*   WrL = (f16*)(ws + 262144);        // [4][1024][32]    = 262144 B
    f16*   VL  = (f16*)(ws + 524288);        // [4][32][1024]    = 262144 B
    float* AL  = (float*)(ws + 786432);      // [1024][4] f32    =  16384 B
    float* BR  = (float*)(ws + 802816);      // [4][1024] f32    =  16384 B
    u64*   AM  = (u64*)(ws + 819200);        // [1024][16] u64   = 131072 B

    k1_proj<<<256, 512, 0, stream>>>(Wl, Wr, Wv, h, a_, adj, Wlh, WrL, VL, AL, BR, AM);
    GATv2Layer_84447646974220_kernel<<<256, 512, 0, stream>>>(
        Wlh, WrL, VL, AM, AL, BR, a_, g_, b_, out);
}

// Round 4
// 95.499 us; speedup vs baseline: 2.3598x; 1.0975x over previous
//
#include <hip/hip_runtime.h>
#include <cstdint>

typedef _Float16 f16;
typedef _Float16 f16x2 __attribute__((ext_vector_type(2)));
typedef _Float16 f16x4 __attribute__((ext_vector_type(4)));
typedef _Float16 f16x8 __attribute__((ext_vector_type(8)));
typedef float    f32x4 __attribute__((ext_vector_type(4)));
typedef unsigned short u16;
typedef unsigned int   u32;

#define LOG2E 1.44269504088896340736f

__device__ __forceinline__ f16x2 habs2(f16x2 v) {
    union { f16x2 h; u32 u; } x; x.h = v; x.u &= 0x7FFF7FFFu; return x.h;
}
#if __has_builtin(__builtin_amdgcn_fdot2)
__device__ __forceinline__ float fdot2f(f16x2 a, f16x2 b, float c) {
    return __builtin_amdgcn_fdot2(a, b, c, false);
}
#else
__device__ __forceinline__ float fdot2f(f16x2 a, f16x2 b, float c) {
    return c + (float)a.x * (float)b.x + (float)a.y * (float)b.y;
}
#endif
#if __has_builtin(__builtin_amdgcn_exp2f)
#define EXP2F __builtin_amdgcn_exp2f
#else
#define EXP2F exp2f
#endif

// ---------------------------------------------------------------------------
// K1: fused prep + projections (round-1 verified structure).
// grid 256 x 384; block = 4 nodes; thread t -> (t>>7 selects W_l/W_r/W_v,
// t&127 is the output column). W f32 read directly as columns (coalesced
// across lanes at fixed k), converted to f16 in registers. h staged to LDS
// as f16 cooperatively.
// Outputs:
//   Wlh f16 [j][128]                 (o = h*32+d)
//   WrL f16 [4h][8c][1024 j][4 l]    (d = 4c+l; coalesced K2 phase-1 loads)
//   VL  f16 [4h][32 d][1024 j]       (MFMA B-frag: 8 contiguous j at fixed d)
//   AL  f32 [1024 i][4 h]  = sum_d 0.6*a_d*Wlh[i,h,d]   (linear score term)
//   BR  f32 [4 h][1024 j]  = sum_d 0.6*a_d*Wrh[j,h,d]
// ---------------------------------------------------------------------------
__global__ __launch_bounds__(384) void k1_proj(
        const float* __restrict__ Wl, const float* __restrict__ Wr,
        const float* __restrict__ Wv, const float* __restrict__ h,
        const float* __restrict__ a_,
        f16* __restrict__ Wlh, f16* __restrict__ WrL, f16* __restrict__ VL,
        float* __restrict__ AL, float* __restrict__ BR) {
    __shared__ __align__(16) f16 hS[4][128];
    const int t    = threadIdx.x;
    const int i0   = blockIdx.x * 4;
    const int wsel = t >> 7, col = t & 127;
    const int lane = t & 63;

    // stage 4 h-rows to LDS as f16 (512 values over 384 threads)
    for (int e = t; e < 512; e += 384)
        ((f16*)hS)[e] = (f16)h[i0 * 128 + e];

    // load this thread's W column (f32, coalesced across lanes per k) -> f16x2
    const float* W = (wsel == 0) ? Wl : ((wsel == 1) ? Wr : Wv);
    f16x2 w2[64];
    #pragma unroll
    for (int c2 = 0; c2 < 64; c2++) {
        f16x2 v;
        v.x = (f16)W[(2 * c2) * 128 + col];
        v.y = (f16)W[(2 * c2 + 1) * 128 + col];
        w2[c2] = v;
    }
    const float asc = 0.6f * a_[col & 31];
    __syncthreads();

    #pragma unroll
    for (int i = 0; i < 4; i++) {
        const int j = i0 + i;
        const f16x2* hr = (const f16x2*)hS[i];
        float acc = 0.f;
        #pragma unroll
        for (int c2 = 0; c2 < 64; c2++) acc = fdot2f(hr[c2], w2[c2], acc);
        const f16 hv = (f16)acc;
        const int hh = col >> 5, dd = col & 31;
        if (wsel == 0) {
            Wlh[j * 128 + col] = hv;
        } else if (wsel == 1) {
            WrL[((hh * 8 + (dd >> 2)) * 1024 + j) * 4 + (dd & 3)] = hv;
        } else {
            VL[(hh * 32 + dd) * 1024 + j] = hv;
        }
        // linear score terms (f32)
        if (wsel < 2) {
            float part = asc * acc;
            #pragma unroll
            for (int off = 1; off < 32; off <<= 1) part += __shfl_xor(part, off);
            if ((lane & 31) == 0) {
                if (wsel == 0) AL[j * 4 + hh] = part;
                else           BR[hh * 1024 + j] = part;
            }
        }
    }
}

// ---------------------------------------------------------------------------
// K2: fused GATv2 attention + MFMA aggregation + LayerNorm + ReLU.
// grid 256 x 512. Block = 4 nodes i. 8 waves: wave w -> (head hh = w&3,
// j-half = w>>2). LDS 37 KB.
// Score: e[i,j,h] = AL[i,h] + BR[h,j] + sum_d (0.4 a_d)|Wlh+Wrh|
// Phase 1 software-pipelined (static ping-pong A/B buffers): loads for
// jb+1 issue before compute of jb, hiding one L2 latency per iteration.
// ---------------------------------------------------------------------------
__global__ __launch_bounds__(512) void GATv2Layer_84447646974220_kernel(
        const f16* __restrict__ Wlh, const f16* __restrict__ WrL,
        const f16* __restrict__ VL,  const int* __restrict__ adj,
        const float* __restrict__ AL, const float* __restrict__ BR,
        const float* __restrict__ a_, const float* __restrict__ ln_g,
        const float* __restrict__ ln_b, float* __restrict__ out) {

    __shared__ __align__(16) f16 ep[4][4][1024];   // [head][row][j]  32768 B
    __shared__ float aggS[2][4][128];              // [half][row][col] 4096 B
    __shared__ float redM[2][4][4];                // [half][head][row]
    __shared__ float redS[2][4][4];

    const int t    = threadIdx.x;
    const int w    = t >> 6;        // 0..7
    const int lane = t & 63;
    const int hh   = w & 3;         // head
    const int half = w >> 2;        // j-half (0: j<512, 1: j>=512)
    const int i0   = blockIdx.x * 4;

    // per-wave constants: q2 = 0.4*a (f16 pairs), Wl head-slices, AL terms
    f16x2 q2[16];
    #pragma unroll
    for (int d2 = 0; d2 < 16; d2++) {
        f16x2 q; q.x = (f16)(0.4f * a_[2 * d2]); q.y = (f16)(0.4f * a_[2 * d2 + 1]);
        q2[d2] = q;
    }
    f16x2 wl2[4][16];
    float al[4];
    #pragma unroll
    for (int ii = 0; ii < 4; ii++) {
        const f16x2* src = (const f16x2*)(Wlh + (i0 + ii) * 128 + hh * 32);
        #pragma unroll
        for (int c2 = 0; c2 < 16; c2++) wl2[ii][c2] = src[c2];
        al[ii] = AL[(i0 + ii) * 4 + hh];          // wave-uniform broadcast
    }

    // ---- phase 1: scores e[i][j], software-pipelined over jb ----
    float maxE[4];
    #pragma unroll
    for (int ii = 0; ii < 4; ii++) maxE[ii] = -__builtin_inff();

    auto LD = [&](int jb, f16x4 (&wr)[8], int (&am)[4], float &bj) {
        int j = half * 512 + jb * 64 + lane;
        #pragma unroll
        for (int c = 0; c < 8; c++)
            wr[c] = *(const f16x4*)(WrL + ((hh * 8 + c) * 1024 + j) * 4);
        #pragma unroll
        for (int ii = 0; ii < 4; ii++) am[ii] = adj[(i0 + ii) * 1024 + j];
        bj = BR[hh * 1024 + j];
    };
    auto CMP = [&](int jb, const f16x4 (&wr)[8], const int (&am)[4], float bj) {
        int j = half * 512 + jb * 64 + lane;
        float e[4];
        #pragma unroll
        for (int ii = 0; ii < 4; ii++) e[ii] = al[ii];
        #pragma unroll
        for (int c = 0; c < 8; c++) {
            #pragma unroll
            for (int ii = 0; ii < 4; ii++) {
                f16x2 t0 = wl2[ii][2 * c]     + wr[c].lo;
                f16x2 t1 = wl2[ii][2 * c + 1] + wr[c].hi;
                e[ii] = fdot2f(q2[2 * c],     habs2(t0), e[ii]);
                e[ii] = fdot2f(q2[2 * c + 1], habs2(t1), e[ii]);
            }
        }
        #pragma unroll
        for (int ii = 0; ii < 4; ii++) {
            float v = am[ii] ? (e[ii] + bj) : -__builtin_inff();
            maxE[ii] = fmaxf(maxE[ii], v);
            ep[hh][ii][j] = (f16)v;
        }
    };

    f16x4 wrA[8], wrB[8];
    int   amA[4], amB[4];
    float bjA, bjB;

    LD(0, wrA, amA, bjA);
    #pragma unroll 1
    for (int jb = 0; jb < 8; jb += 2) {
        LD(jb + 1, wrB, amB, bjB);
        CMP(jb, wrA, amA, bjA);
        if (jb + 2 < 8) LD(jb + 2, wrA, amA, bjA);
        CMP(jb + 1, wrB, amB, bjB);
    }

    // ---- phase 2: softmax (cross-half max/sum through LDS) ----
    #pragma unroll
    for (int ii = 0; ii < 4; ii++) {
        float M = maxE[ii];
        #pragma unroll
        for (int off = 32; off > 0; off >>= 1) M = fmaxf(M, __shfl_xor(M, off));
        if (lane == 0) redM[half][hh][ii] = M;
    }
    __syncthreads();

    #pragma unroll
    for (int ii = 0; ii < 4; ii++) {
        float M = fmaxf(redM[0][hh][ii], redM[1][hh][ii]);
        f16x8 v0 = *(f16x8*)&ep[hh][ii][half * 512 + lane * 8];
        float pb[8], l = 0.f;
        #pragma unroll
        for (int e = 0; e < 8; e++) pb[e] = EXP2F(((float)v0[e] - M) * LOG2E);
        #pragma unroll
        for (int e = 0; e < 8; e++) { v0[e] = (f16)pb[e]; l += pb[e]; }
        *(f16x8*)&ep[hh][ii][half * 512 + lane * 8] = v0;
        #pragma unroll
        for (int off = 32; off > 0; off >>= 1) l += __shfl_xor(l, off);
        if (lane == 0) redS[half][hh][ii] = l;
    }
    __syncthreads();

    float lr[4];
    #pragma unroll
    for (int ii = 0; ii < 4; ii++)
        lr[ii] = 1.0f / (redS[0][hh][ii] + redS[1][hh][ii]);

    // ---- phase 3: agg = p @ V via MFMA ----
    // A-frag: A[m=lane&15][k=(lane>>4)*8+jj]; rows 4..15 duplicate rows 0..3
    // (m3 = lane&3) — garbage C-rows discarded. B-frag: B[k][n=lane&15] from
    // VL[d=n][j=k] (contiguous j). C/D: col=lane&15, row=(lane>>4)*4+reg.
    // unroll 2: VL loads of tile n+1 overlap MFMA of tile n.
    f32x4 acc0 = {0.f, 0.f, 0.f, 0.f}, acc1 = {0.f, 0.f, 0.f, 0.f};
    const int q8  = (lane >> 4) << 3;
    const int m3  = lane & 3;
    const int n15 = lane & 15;

    #pragma unroll 2
    for (int jt4 = 0; jt4 < 4; jt4++) {
        int jt = half * 4 + jt4;
        #pragma unroll
        for (int kk = 0; kk < 4; kk++) {
            int ko = jt * 128 + kk * 32 + q8;
            f16x8 af = *(const f16x8*)&ep[hh][m3][ko];
            f16x8 b0 = *(const f16x8*)(VL + (hh * 32 + n15) * 1024 + ko);
            f16x8 b1 = *(const f16x8*)(VL + (hh * 32 + 16 + n15) * 1024 + ko);
            acc0 = __builtin_amdgcn_mfma_f32_16x16x32_f16(af, b0, acc0, 0, 0, 0);
            acc1 = __builtin_amdgcn_mfma_f32_16x16x32_f16(af, b1, acc1, 0, 0, 0);
        }
    }

    if (lane < 16) {
        #pragma unroll
        for (int r = 0; r < 4; r++) {
            aggS[half][r][hh * 32 + lane]      = acc0[r] * lr[r];
            aggS[half][r][hh * 32 + 16 + lane] = acc1[r] * lr[r];
        }
    }
    __syncthreads();

    // ---- phase 4: LayerNorm + ReLU (waves 0..3, one node-row each) ----
    if (w < 4) {
        float x0 = aggS[0][w][lane]      + aggS[1][w][lane];
        float x1 = aggS[0][w][lane + 64] + aggS[1][w][lane + 64];
        float s = x0 + x1, sq = x0 * x0 + x1 * x1;
        #pragma unroll
        for (int off = 32; off > 0; off >>= 1) {
            s  += __shfl_xor(s, off);
            sq += __shfl_xor(sq, off);
        }
        float mean = s * (1.f / 128.f);
        float var  = sq * (1.f / 128.f) - mean * mean;
        float rs   = rsqrtf(var + 1e-5f);
        float y0 = fmaxf((x0 - mean) * rs * ln_g[lane]      + ln_b[lane],      0.f);
        float y1 = fmaxf((x1 - mean) * rs * ln_g[lane + 64] + ln_b[lane + 64], 0.f);
        out[(i0 + w) * 128 + lane]      = y0;
        out[(i0 + w) * 128 + 64 + lane] = y1;
    }
}

// ---------------------------------------------------------------------------
extern "C" void kernel_launch(void* const* d_in, const int* in_sizes, int n_in,
                              void* d_out, int out_size, void* d_ws, size_t ws_size,
                              hipStream_t stream) {
    const float* h   = (const float*)d_in[0];
    const int*   adj = (const int*)d_in[1];
    const float* Wl  = (const float*)d_in[2];
    const float* Wr  = (const float*)d_in[3];
    const float* Wv  = (const float*)d_in[4];
    const float* a_  = (const float*)d_in[5];
    const float* g_  = (const float*)d_in[6];
    const float* b_  = (const float*)d_in[7];
    float* out = (float*)d_out;

    char* ws = (char*)d_ws;
    f16*   Wlh = (f16*)(ws);                 // 1024*128 f16    = 262144 B
    f16*   WrL = (f16*)(ws + 262144);        // [4][8][1024][4] = 262144 B
    f16*   VL  = (f16*)(ws + 524288);        // [4][32][1024]   = 262144 B
    float* AL  = (float*)(ws + 786432);      // [1024][4] f32   =  16384 B
    float* BR  = (float*)(ws + 802816);      // [4][1024] f32   =  16384 B

    k1_proj<<<256, 384, 0, stream>>>(Wl, Wr, Wv, h, a_, Wlh, WrL, VL, AL, BR);
    GATv2Layer_84447646974220_kernel<<<256, 512, 0, stream>>>(
        Wlh, WrL, VL, adj, AL, BR, a_, g_, b_, out);
}